// Round 13
// baseline (690.034 us; speedup 1.0000x reference)
//
#include <hip/hip_runtime.h>

#define H 128
#define KV 256
#define CPAD 16   // counters padded to one per 64B line (R12: line-contention fix)

typedef short bf16x8 __attribute__((ext_vector_type(8)));
typedef float f32x4 __attribute__((ext_vector_type(4)));
union FragU { uint4 u; bf16x8 s; };

#define LOG2E 1.44269504088896f
#define LN2   0.69314718055995f

__device__ __forceinline__ float bf2f(unsigned short u) {
  return __uint_as_float(((unsigned)u) << 16);
}
__device__ __forceinline__ unsigned short f2bf(float f) {
  unsigned b = __float_as_uint(f);
  b += 0x7FFFu + ((b >> 16) & 1u);   // round-to-nearest-even
  return (unsigned short)(b >> 16);
}
// fast silu: x * rcp(1+exp(-x)); v_rcp_f32 ~1ulp, well inside absmax budget.
__device__ __forceinline__ float fsilu(float x) {
  return x * __builtin_amdgcn_rcpf(1.f + __expf(-x));
}
// raw v_exp_f32: D = 2^S0 (ISA-doc semantics)
__device__ __forceinline__ float fexp2(float x) {
  float r;
  asm("v_exp_f32 %0, %1" : "=v"(r) : "v"(x));
  return r;
}
// silu in log2-domain: input y = x*log2e; returns silu(x)*log2e
// (the ln2 is pre-folded into the Wc2 table).
__device__ __forceinline__ float fsilu2(float y) {
  return y * __builtin_amdgcn_rcpf(1.f + fexp2(-y));
}
// rad6 = unique entries of the symmetric radial matrix [00,11,22,01,02,12]
__device__ __forceinline__ void rad6_from_cd(const float cd[9], float r6[6]) {
  r6[0] = cd[0]*cd[0] + cd[1]*cd[1] + cd[2]*cd[2];
  r6[1] = cd[3]*cd[3] + cd[4]*cd[4] + cd[5]*cd[5];
  r6[2] = cd[6]*cd[6] + cd[7]*cd[7] + cd[8]*cd[8];
  r6[3] = cd[0]*cd[3] + cd[1]*cd[4] + cd[2]*cd[5];
  r6[4] = cd[0]*cd[6] + cd[1]*cd[7] + cd[2]*cd[8];
  r6[5] = cd[3]*cd[6] + cd[4]*cd[7] + cd[5]*cd[8];
}
__constant__ int c_pa[6] = {0,4,8,1,2,5};
__constant__ int c_pb[6] = {0,0,0,3,6,7};

__global__ __launch_bounds__(256) void k_zero(float* __restrict__ p, int n) {
  int i = blockIdx.x * 256 + threadIdx.x;
  if (i < n) p[i] = 0.f;
}
__global__ __launch_bounds__(256) void k_sentinel(float* __restrict__ out, int n) {
  int i = blockIdx.x * 256 + threadIdx.x;
  if (i < n) out[i] = 1000.0f;
}

// pack Wc1 (128x512 fp32) into bf16 fragment order (verified R5-R10).
// Pre-scaled by log2e (hn arrives in log2-domain for fsilu2; hn feeds ONLY
// k_edge_mlp3).
__global__ __launch_bounds__(256) void k_prep_w1(const float* __restrict__ Wc1,
                                                 uint4* __restrict__ w1f) {
  int t = blockIdx.x*256 + threadIdx.x;    // 8192 total
  int g = t >> 6, lane = t & 63;
  int q = g >> 5, kk = (g >> 3) & 3, mt = g & 7;
  int o = q*128 + mt*16 + (lane & 15);
  int kbase = kk*32 + (lane >> 4)*8;
  unsigned s[8];
  #pragma unroll
  for (int j = 0; j < 8; ++j) s[j] = f2bf(Wc1[(kbase+j)*512 + o] * LOG2E);
  uint4 u;
  u.x = s[0] | (s[1]<<16); u.y = s[2] | (s[3]<<16);
  u.z = s[4] | (s[5]<<16); u.w = s[6] | (s[7]<<16);
  w1f[g*64 + lane] = u;
}

// pack Wcat = [Wq | Wkv-even(k) | Wkv-odd(v)] (128 x 384) into bf16 hi/lo
// MFMA A-frags (bf16x3 trick: w = hi + lo, each bf16). g = (q*4+kk)*8+mt.
__global__ __launch_bounds__(256) void k_prep_wcat(
    const float* __restrict__ Wq, const float* __restrict__ Wkv,
    uint4* __restrict__ wcat_hi, uint4* __restrict__ wcat_lo)
{
  int t = blockIdx.x*256 + threadIdx.x;   // 6144 total
  if (t >= 96*64) return;
  int g = t >> 6, lane = t & 63;
  int mt = g & 7, kk = (g >> 3) & 3, q = g >> 5;
  int oo = mt*16 + (lane & 15);       // 0..127 within section
  int kbase = kk*32 + (lane >> 4)*8;
  unsigned shi[8], slo[8];
  #pragma unroll
  for (int j = 0; j < 8; ++j) {
    int k = kbase + j;
    float w;
    if (q == 0)      w = Wq[k*H + oo];
    else if (q == 1) w = Wkv[(9 + k)*KV + 2*oo];
    else             w = Wkv[(9 + k)*KV + 2*oo + 1];
    unsigned hi = f2bf(w);
    float lo = w - bf2f((unsigned short)hi);
    shi[j] = hi; slo[j] = f2bf(lo);
  }
  uint4 uh, ul;
  uh.x = shi[0]|(shi[1]<<16); uh.y = shi[2]|(shi[3]<<16);
  uh.z = shi[4]|(shi[5]<<16); uh.w = shi[6]|(shi[7]<<16);
  ul.x = slo[0]|(slo[1]<<16); ul.y = slo[2]|(slo[3]<<16);
  ul.z = slo[4]|(slo[5]<<16); ul.w = slo[6]|(slo[7]<<16);
  wcat_hi[g*64 + lane] = uh;
  wcat_lo[g*64 + lane] = ul;
}

// Wr6[6][512] = sym-folded (Wvo @ Wc1)
__global__ __launch_bounds__(256) void k_prep_wr6(const float* __restrict__ Wkv,
                                                  const float* __restrict__ Wc1,
                                                  float* __restrict__ Wr6) {
  int idx = blockIdx.x*256 + threadIdx.x;   // 3072
  if (idx >= 6*512) return;
  int d = idx >> 9, o = idx & 511;
  float s = 0.f;
  for (int k = 0; k < 128; ++k) {
    float w = Wkv[c_pa[d]*KV + 2*k + 1];
    if (d >= 3) w += Wkv[c_pb[d]*KV + 2*k + 1];
    s += w * Wc1[k*512 + o];
  }
  Wr6[d*512 + o] = s;
}

// pack Wr6 into bf16 MFMA A-frags (scaled by log2e, matching hn's domain)
// and Wc2 into quad-broadcast float4 table (scaled by ln2 to undo it).
__global__ __launch_bounds__(256) void k_prep_ar6(
    const float* __restrict__ Wr6, const float* __restrict__ Wc2,
    uint4* __restrict__ ar6f, float* __restrict__ w2p)
{
  int t = threadIdx.x;
  for (int i = t; i < 512; i += 256) {
    int ch = i;
    unsigned b0 = (unsigned)f2bf(Wr6[0*512+ch]*LOG2E) | ((unsigned)f2bf(Wr6[1*512+ch]*LOG2E)<<16);
    unsigned b1 = (unsigned)f2bf(Wr6[2*512+ch]*LOG2E) | ((unsigned)f2bf(Wr6[3*512+ch]*LOG2E)<<16);
    unsigned b2 = (unsigned)f2bf(Wr6[4*512+ch]*LOG2E) | ((unsigned)f2bf(Wr6[5*512+ch]*LOG2E)<<16);
    ar6f[i] = make_uint4(b0, b1, b2, 0u);
  }
  for (int i = t; i < 1536; i += 256) {
    int i4 = i & 3, rest = i >> 2;
    int k = rest % 3, g = rest / 3;
    int ch = (g >> 2)*16 + (g & 3)*4 + i4;
    w2p[i] = Wc2[ch*3 + k] * LN2;
  }
}

// ---------- dual counting sort (row + col) ----------
// R12: back to 1 edge/thread (R11's 4-edge batching cut occupancy 62->19%
// and REGRESSED: atomic kernels need wave-count, not per-thread ILP).
// Counters padded to 1-per-64B-line (CPAD) to break memory-side line-lock
// serialization (50k counters were sharing 3.1k lines).
__global__ __launch_bounds__(256) void k_hist2(const int* __restrict__ row,
                                               const int* __restrict__ col,
                                               int* __restrict__ cr,
                                               int* __restrict__ cc, int E) {
  int e = blockIdx.x*256 + threadIdx.x;
  if (e >= E) return;
  atomicAdd(&cr[(size_t)row[e]*CPAD], 1);
  atomicAdd(&cc[(size_t)col[e]*CPAD], 1);
}

__global__ __launch_bounds__(1024) void k_scan2(
    const int* __restrict__ cr, int* __restrict__ rstart, int* __restrict__ rcur,
    const int* __restrict__ cc, int* __restrict__ cstart, int* __restrict__ ccur,
    int n) {
  const int* counts = (blockIdx.x == 0) ? cr : cc;
  int* start = (blockIdx.x == 0) ? rstart : cstart;
  int* cursor = (blockIdx.x == 0) ? rcur : ccur;
  __shared__ int wsum[16];
  __shared__ int carry_s;
  const int tid = threadIdx.x, lane = tid & 63, wid = tid >> 6;
  if (tid == 0) carry_s = 0;
  __syncthreads();
  for (int base = 0; base < n; base += 1024) {
    int i = base + tid;
    int v = (i < n) ? counts[(size_t)i*CPAD] : 0;
    int s = v;
    #pragma unroll
    for (int off = 1; off < 64; off <<= 1) {
      int t = __shfl_up(s, off, 64);
      if (lane >= off) s += t;
    }
    if (lane == 63) wsum[wid] = s;
    __syncthreads();
    if (wid == 0 && lane < 16) {
      int w = wsum[lane];
      #pragma unroll
      for (int off = 1; off < 16; off <<= 1) {
        int t = __shfl_up(w, off, 16);
        if (lane >= off) w += t;
      }
      wsum[lane] = w;
    }
    __syncthreads();
    int wexcl = (wid == 0) ? 0 : wsum[wid-1];
    int excl = carry_s + wexcl + (s - v);
    if (i < n) { start[i] = excl; cursor[(size_t)i*CPAD] = excl; }
    __syncthreads();
    if (tid == 0) carry_s += wsum[15];
    __syncthreads();
  }
  if (threadIdx.x == 0) start[n] = carry_s;
}

__global__ __launch_bounds__(256) void k_scatter2(
    const int* __restrict__ row, const int* __restrict__ col,
    int* __restrict__ rcur, int* __restrict__ eidx,
    int* __restrict__ ccur, int* __restrict__ eidx2, int E) {
  int e = blockIdx.x*256 + threadIdx.x;
  if (e >= E) return;
  int pos = atomicAdd(&rcur[(size_t)row[e]*CPAD], 1);
  eidx[pos] = e;
  int pos2 = atomicAdd(&ccur[(size_t)col[e]*CPAD], 1);
  eidx2[pos2] = e;
}

// ---------- K1: node projection as bf16x3 MFMA GEMM (verified R4) ----------
// kn stored bf16 (R12, verified: halves alpha gather traffic).
__global__ __launch_bounds__(256) void k_node_mfma(
    const float* __restrict__ h, const uint4* __restrict__ wcat_hi,
    const uint4* __restrict__ wcat_lo, const float* __restrict__ bq,
    const float* __restrict__ bkv, float* __restrict__ qn,
    unsigned short* __restrict__ kn, unsigned short* __restrict__ vn, int N)
{
  __shared__ unsigned vhi[128*64];
  __shared__ unsigned vlo[128*64];
  const int tid = threadIdx.x;
  const int wid = tid >> 6, lane = tid & 63;
  const int quad = lane >> 4, colc = lane & 15;
  const int n0 = blockIdx.x * 128;
  for (int i = 0; i < 32; ++i) {
    int el = i*4 + wid;
    int c = n0 + el; if (c >= N) c = N - 1;
    float2 hv = *((const float2*)(h + (size_t)c*H + 2*lane));
    unsigned h0 = f2bf(hv.x), h1 = f2bf(hv.y);
    float l0 = hv.x - bf2f((unsigned short)h0);
    float l1 = hv.y - bf2f((unsigned short)h1);
    int sw = el*64 + (((lane>>2) ^ (el&15))<<2) + (lane&3);
    vhi[sw] = h0 | (h1<<16);
    vlo[sw] = (unsigned)f2bf(l0) | ((unsigned)f2bf(l1)<<16);
  }
  __syncthreads();
  const int ntbase = wid*32;
  for (int q = 0; q < 3; ++q) {
    f32x4 acc[8][2];
    #pragma unroll
    for (int mt = 0; mt < 8; ++mt)
      #pragma unroll
      for (int nt = 0; nt < 2; ++nt) acc[mt][nt] = (f32x4){0.f,0.f,0.f,0.f};
    #pragma unroll
    for (int kk = 0; kk < 4; ++kk) {
      FragU bhi[2], blo[2];
      #pragma unroll
      for (int nt = 0; nt < 2; ++nt) {
        int rrow = ntbase + nt*16 + colc;
        int ad = rrow*64 + (((kk*4 + quad) ^ (rrow&15))<<2);
        bhi[nt].u = *((const uint4*)&vhi[ad]);
        blo[nt].u = *((const uint4*)&vlo[ad]);
      }
      #pragma unroll
      for (int mt = 0; mt < 8; ++mt) {
        FragU ahi, alo;
        int gidx = (((q*4+kk)*8+mt)<<6) + lane;
        ahi.u = wcat_hi[gidx];
        alo.u = wcat_lo[gidx];
        #pragma unroll
        for (int nt = 0; nt < 2; ++nt) {
          acc[mt][nt] = __builtin_amdgcn_mfma_f32_16x16x32_bf16(
              ahi.s, bhi[nt].s, acc[mt][nt], 0, 0, 0);
          acc[mt][nt] = __builtin_amdgcn_mfma_f32_16x16x32_bf16(
              ahi.s, blo[nt].s, acc[mt][nt], 0, 0, 0);
          acc[mt][nt] = __builtin_amdgcn_mfma_f32_16x16x32_bf16(
              alo.s, bhi[nt].s, acc[mt][nt], 0, 0, 0);
        }
      }
    }
    #pragma unroll
    for (int mt = 0; mt < 8; ++mt)
      #pragma unroll
      for (int nt = 0; nt < 2; ++nt) {
        int node = n0 + ntbase + nt*16 + colc;
        if (node >= N) continue;
        int chq = mt*16 + quad*4;     // 0..127 within section
        if (q == 0) {
          float4 b = *((const float4*)(bq + chq));
          float4 o;
          o.x = acc[mt][nt][0] + b.x; o.y = acc[mt][nt][1] + b.y;
          o.z = acc[mt][nt][2] + b.z; o.w = acc[mt][nt][3] + b.w;
          *((float4*)(qn + (size_t)node*H + chq)) = o;
        } else if (q == 1) {
          unsigned s0 = f2bf(acc[mt][nt][0] + bkv[2*(chq+0)]);
          unsigned s1 = f2bf(acc[mt][nt][1] + bkv[2*(chq+1)]);
          unsigned s2 = f2bf(acc[mt][nt][2] + bkv[2*(chq+2)]);
          unsigned s3 = f2bf(acc[mt][nt][3] + bkv[2*(chq+3)]);
          *((uint2*)(kn + (size_t)node*H + chq)) =
              make_uint2(s0 | (s1<<16), s2 | (s3<<16));
        } else {
          unsigned s0 = f2bf(acc[mt][nt][0] + bkv[2*(chq+0)+1]);
          unsigned s1 = f2bf(acc[mt][nt][1] + bkv[2*(chq+1)+1]);
          unsigned s2 = f2bf(acc[mt][nt][2] + bkv[2*(chq+2)+1]);
          unsigned s3 = f2bf(acc[mt][nt][3] + bkv[2*(chq+3)+1]);
          *((uint2*)(vn + (size_t)node*H + chq)) =
              make_uint2(s0 | (s1<<16), s2 | (s3<<16));
        }
      }
  }
}

// ---------- K2pre: qwn[n][6] = q_n @ Wke6^T ----------
__global__ __launch_bounds__(256) void k_qw(
    const float* __restrict__ qn, const float* __restrict__ Wkv,
    float* __restrict__ qwn, int N)
{
  __shared__ float wke6[6*128];
  const int tid = threadIdx.x;
  for (int idx = tid; idx < 6*128; idx += 256) {
    int d = idx >> 7, j = idx & 127;
    float we = Wkv[c_pa[d]*KV + 2*j];
    if (d >= 3) we += Wkv[c_pb[d]*KV + 2*j];
    wke6[idx] = we;
  }
  __syncthreads();
  const int wid = tid >> 6, lane = tid & 63;
  const int n = blockIdx.x*4 + wid;
  if (n >= N) return;
  float q0 = qn[(size_t)n*H + lane];
  float q1 = qn[(size_t)n*H + 64 + lane];
  #pragma unroll
  for (int d = 0; d < 6; ++d) {
    float p = q0*wke6[d*128 + lane] + q1*wke6[d*128 + 64 + lane];
    #pragma unroll
    for (int m = 32; m > 0; m >>= 1) p += __shfl_xor(p, m, 64);
    if (lane == 0) qwn[(size_t)n*6 + d] = p;
  }
}

// ---------- K2a: edge-parallel raw alpha. lane = edge. kn in bf16. ----------
__global__ __launch_bounds__(256) void k_edge_alpha(
    const float* __restrict__ coord, const int* __restrict__ row,
    const int* __restrict__ col, const int* __restrict__ eidx,
    const float* __restrict__ qn, const unsigned short* __restrict__ knb,
    const float* __restrict__ qwn, float* __restrict__ aout, int E)
{
  int j = blockIdx.x*256 + threadIdx.x;
  if (j >= E) return;
  int e = eidx[j];
  int r = row[e], c = col[e];
  const float4* qp = (const float4*)(qn + (size_t)r*H);
  const uint4* kp = (const uint4*)(knb + (size_t)c*H);
  float d0 = 0.f, d1 = 0.f, d2 = 0.f, d3 = 0.f;
  #pragma unroll 4
  for (int i = 0; i < 16; ++i) {
    uint4 kv = kp[i];
    float4 q0 = qp[2*i], q1 = qp[2*i+1];
    d0 += q0.x*__uint_as_float(kv.x << 16) + q0.y*__uint_as_float(kv.x & 0xffff0000u);
    d1 += q0.z*__uint_as_float(kv.y << 16) + q0.w*__uint_as_float(kv.y & 0xffff0000u);
    d2 += q1.x*__uint_as_float(kv.z << 16) + q1.y*__uint_as_float(kv.z & 0xffff0000u);
    d3 += q1.z*__uint_as_float(kv.w << 16) + q1.w*__uint_as_float(kv.w & 0xffff0000u);
  }
  float cd[9], r6[6];
  #pragma unroll
  for (int i = 0; i < 9; ++i)
    cd[i] = coord[(size_t)r*9 + i] - coord[(size_t)c*9 + i];
  rad6_from_cd(cd, r6);
  float ar = (d0 + d1) + (d2 + d3);
  #pragma unroll
  for (int d = 0; d < 6; ++d) ar += r6[d]*qwn[(size_t)r*6 + d];
  aout[e] = ar;
}

// ---------- K2b: exact per-row softmax + h_out ----------
__global__ __launch_bounds__(256) void k_row_soft(
    const float* __restrict__ h, const float* __restrict__ coord,
    const int* __restrict__ col, const float* __restrict__ Wkv,
    const int* __restrict__ row_start, const int* __restrict__ eidx,
    const unsigned* __restrict__ vnu, float* __restrict__ aout,
    float* __restrict__ hout, int N)
{
  __shared__ float wvo6[6*128];
  __shared__ float ws[4][64];
  __shared__ int   cs[4][64];
  const int tid = threadIdx.x;
  for (int idx = tid; idx < 6*128; idx += 256) {
    int d = idx >> 7, jj = idx & 127;
    float wo = Wkv[c_pa[d]*KV + 2*jj + 1];
    if (d >= 3) wo += Wkv[c_pb[d]*KV + 2*jj + 1];
    wvo6[idx] = wo;
  }
  __syncthreads();
  const int wid = tid >> 6, lane = tid & 63;
  const int r = blockIdx.x*4 + wid;
  if (r >= N) return;
  const int js = row_start[r], je = row_start[r+1];
  const int deg = je - js;
  float crd[9];
  #pragma unroll
  for (int i = 0; i < 9; ++i) crd[i] = coord[(size_t)r*9 + i];

  float t6s[6];
  float mn, invl;
  const bool big = (deg > 64);
  if (!big) {
    int e = 0, c = 0;
    float ar = -1e30f;
    float r6[6] = {0.f,0.f,0.f,0.f,0.f,0.f};
    if (lane < deg) {
      e = eidx[js + lane];
      ar = aout[e];
      c = col[e];
      float cd[9];
      #pragma unroll
      for (int i = 0; i < 9; ++i) cd[i] = crd[i] - coord[(size_t)c*9 + i];
      rad6_from_cd(cd, r6);
    }
    float mx = ar;
    #pragma unroll
    for (int m = 32; m > 0; m >>= 1) mx = fmaxf(mx, __shfl_xor(mx, m, 64));
    mn = mx;
    float w = (lane < deg) ? __expf(ar - mn) : 0.f;
    float lw = w;
    #pragma unroll
    for (int m = 32; m > 0; m >>= 1) lw += __shfl_xor(lw, m, 64);
    invl = (deg > 0) ? 1.f/lw : 0.f;
    #pragma unroll
    for (int d = 0; d < 6; ++d) {
      float v = w*r6[d];
      #pragma unroll
      for (int m = 32; m > 0; m >>= 1) v += __shfl_xor(v, m, 64);
      t6s[d] = v;
    }
    ws[wid][lane] = w;
    cs[wid][lane] = c;
    if (lane < deg) aout[e] = w*invl;
  } else {
    float mx = -1e30f;
    for (int j2 = js + lane; j2 < je; j2 += 64)
      mx = fmaxf(mx, aout[eidx[j2]]);
    #pragma unroll
    for (int m = 32; m > 0; m >>= 1) mx = fmaxf(mx, __shfl_xor(mx, m, 64));
    mn = mx;
    float lp = 0.f;
    float t6p[6] = {0.f,0.f,0.f,0.f,0.f,0.f};
    for (int j2 = js + lane; j2 < je; j2 += 64) {
      int e = eidx[j2];
      float ar = aout[e];
      float w = __expf(ar - mn);
      lp += w;
      int c = col[e];
      float cd[9], r6[6];
      #pragma unroll
      for (int i = 0; i < 9; ++i) cd[i] = crd[i] - coord[(size_t)c*9 + i];
      rad6_from_cd(cd, r6);
      #pragma unroll
      for (int d = 0; d < 6; ++d) t6p[d] += w*r6[d];
    }
    #pragma unroll
    for (int m = 32; m > 0; m >>= 1) lp += __shfl_xor(lp, m, 64);
    invl = (deg > 0) ? 1.f/lp : 0.f;
    #pragma unroll
    for (int d = 0; d < 6; ++d) {
      float v = t6p[d];
      #pragma unroll
      for (int m = 32; m > 0; m >>= 1) v += __shfl_xor(v, m, 64);
      t6s[d] = v;
    }
  }
  float acc0 = 0.f, acc1 = 0.f;
  if (!big) {
    #pragma unroll 4
    for (int t = 0; t < deg; ++t) {
      float w = ws[wid][t];
      int c = cs[wid][t];
      unsigned v = vnu[(size_t)c*64 + lane];
      acc0 += w*__uint_as_float(v << 16);
      acc1 += w*__uint_as_float(v & 0xffff0000u);
    }
  } else {
    for (int t = js; t < je; ++t) {
      int e = eidx[t];
      float ar = aout[e];
      float w = __expf(ar - mn);
      int c = col[e];
      unsigned v = vnu[(size_t)c*64 + lane];
      acc0 += w*__uint_as_float(v << 16);
      acc1 += w*__uint_as_float(v & 0xffff0000u);
    }
    for (int j2 = js + lane; j2 < je; j2 += 64) {
      int e = eidx[j2];
      aout[e] = __expf(aout[e] - mn)*invl;
    }
  }
  float o0 = acc0, o1 = acc1;
  #pragma unroll
  for (int d = 0; d < 6; ++d) {
    o0 += t6s[d]*wvo6[d*128 + 2*lane];
    o1 += t6s[d]*wvo6[d*128 + 2*lane + 1];
  }
  hout[(size_t)r*H + 2*lane]     = h[(size_t)r*H + 2*lane]     + o0*invl;
  hout[(size_t)r*H + 2*lane + 1] = h[(size_t)r*H + 2*lane + 1] + o1*invl;
}

// ---------- K4a: hn[N][512] bf16 = vn @ (Wc1*log2e) (node MFMA GEMM) ----------
__global__ __launch_bounds__(256) void k_node_hn(
    const unsigned* __restrict__ vnu, const uint4* __restrict__ w1f,
    unsigned short* __restrict__ hn, int N)
{
  __shared__ unsigned vt[128*64];
  __shared__ unsigned short hno[128*128];
  const int tid = threadIdx.x;
  const int wid = tid >> 6, lane = tid & 63;
  const int quad = lane >> 4, colc = lane & 15;
  const int n0 = blockIdx.x * 128;
  for (int i = 0; i < 32; ++i) {
    int el = i*4 + wid;
    int c = n0 + el; if (c >= N) c = N - 1;
    unsigned pk = vnu[(size_t)c*64 + lane];
    vt[el*64 + (((lane>>2) ^ (el&15))<<2) + (lane&3)] = pk;
  }
  __syncthreads();
  const int ntbase = wid*32;
  for (int q = 0; q < 4; ++q) {
    f32x4 acc[8][2];
    #pragma unroll
    for (int mt = 0; mt < 8; ++mt)
      #pragma unroll
      for (int nt = 0; nt < 2; ++nt) acc[mt][nt] = (f32x4){0.f,0.f,0.f,0.f};
    #pragma unroll
    for (int kk = 0; kk < 4; ++kk) {
      FragU bfr[2];
      #pragma unroll
      for (int nt = 0; nt < 2; ++nt) {
        int rrow = ntbase + nt*16 + colc;
        int chunk = kk*4 + quad;
        bfr[nt].u = *((const uint4*)&vt[rrow*64 + ((chunk ^ (rrow&15))<<2)]);
      }
      #pragma unroll
      for (int mt = 0; mt < 8; ++mt) {
        FragU afr;
        afr.u = w1f[(((q*4+kk)*8+mt)<<6) + lane];
        #pragma unroll
        for (int nt = 0; nt < 2; ++nt)
          acc[mt][nt] = __builtin_amdgcn_mfma_f32_16x16x32_bf16(
              afr.s, bfr[nt].s, acc[mt][nt], 0, 0, 0);
      }
    }
    #pragma unroll
    for (int mt = 0; mt < 8; ++mt)
      #pragma unroll
      for (int nt = 0; nt < 2; ++nt) {
        int node = ntbase + nt*16 + colc;
        int o = mt*16 + quad*4;
        unsigned lo = (unsigned)f2bf(acc[mt][nt][0]) | ((unsigned)f2bf(acc[mt][nt][1]) << 16);
        unsigned hi = (unsigned)f2bf(acc[mt][nt][2]) | ((unsigned)f2bf(acc[mt][nt][3]) << 16);
        *((uint2*)&hno[node*128 + o]) = make_uint2(lo, hi);
      }
    __syncthreads();
    const uint4* hns = (const uint4*)hno;
    #pragma unroll
    for (int it = 0; it < 8; ++it) {
      int u = it*256 + tid;
      int node = u >> 4, within = u & 15;
      int gn = n0 + node;
      if (gn < N) ((uint4*)hn)[(size_t)gn*64 + q*16 + within] = hns[node*16 + within];
    }
    __syncthreads();
  }
}

// ---------- K4b: mlpout via MFMA + fsilu2, [tbase,tend) range split ----------
__global__ __launch_bounds__(512) void k_edge_mlp3(
    const float* __restrict__ coord, const int* __restrict__ row,
    const int* __restrict__ col, const uint4* __restrict__ ar6f,
    const float* __restrict__ w2p, const unsigned short* __restrict__ hn,
    const int* __restrict__ eidx2, float* __restrict__ mlpout, int E,
    int tbase, int tend)
{
  __shared__ uint4 a8[512];
  __shared__ float4 w2s[384];
  const int tid = threadIdx.x;
  {
    const uint4* s4 = (const uint4*)w2p;
    for (int i = tid; i < 512; i += 512) a8[i] = ar6f[i];
    if (tid < 384) w2s[tid] = ((const float4*)s4)[tid];
  }
  __syncthreads();
  const int wid = tid >> 6, lane = tid & 63;
  const int l15 = lane & 15, quad = lane >> 4;
  const bool q0 = (quad == 0);

  int gw = blockIdx.x*8 + wid;
  int nw = gridDim.x*8;
  for (int t = tbase + gw; t < tend; t += nw) {
    int j = t*64 + lane;
    int jc = (j < E) ? j : (E - 1);
    int e = eidx2[jc];
    int c = col[e];
    int r = row[e];
    float cd[9], r6[6];
    #pragma unroll
    for (int i = 0; i < 9; ++i)
      cd[i] = coord[(size_t)r*9 + i] - coord[(size_t)c*9 + i];
    rad6_from_cd(cd, r6);
    unsigned pw0 = (unsigned)f2bf(r6[0]) | ((unsigned)f2bf(r6[1]) << 16);
    unsigned pw1 = (unsigned)f2bf(r6[2]) | ((unsigned)f2bf(r6[3]) << 16);
    unsigned pw2 = (unsigned)f2bf(r6[4]) | ((unsigned)f2bf(r6[5]) << 16);
    FragU bfr[4];
    const unsigned short* hb[4];
    #pragma unroll
    for (int f = 0; f < 4; ++f) {
      int src = f*16 + l15;
      unsigned w0 = __shfl(pw0, src, 64);
      unsigned w1 = __shfl(pw1, src, 64);
      unsigned w2_ = __shfl(pw2, src, 64);
      bfr[f].u = make_uint4(q0 ? w0 : 0u, q0 ? w1 : 0u, q0 ? w2_ : 0u, 0u);
      int nb = __shfl(c, src, 64);
      hb[f] = hn + (size_t)nb*512 + quad*4;
    }
    float cv[4][3];
    #pragma unroll
    for (int f = 0; f < 4; ++f) { cv[f][0]=0.f; cv[f][1]=0.f; cv[f][2]=0.f; }

    #pragma unroll 2
    for (int m = 0; m < 32; ++m) {
      uint4 av = a8[m*16 + l15];
      FragU afr;
      afr.u = make_uint4(q0 ? av.x : 0u, q0 ? av.y : 0u, q0 ? av.z : 0u, 0u);
      float4 wk0 = w2s[(m*4 + quad)*3 + 0];
      float4 wk1 = w2s[(m*4 + quad)*3 + 1];
      float4 wk2 = w2s[(m*4 + quad)*3 + 2];
      #pragma unroll
      for (int f = 0; f < 4; ++f) {
        uint2 hv = *((const uint2*)(hb[f] + m*16));
        f32x4 cin;
        cin[0] = __uint_as_float(hv.x << 16);
        cin[1] = __uint_as_float(hv.x & 0xffff0000u);
        cin[2] = __uint_as_float(hv.y << 16);
        cin[3] = __uint_as_float(hv.y & 0xffff0000u);
        f32x4 d = __builtin_amdgcn_mfma_f32_16x16x32_bf16(
            afr.s, bfr[f].s, cin, 0, 0, 0);
        float s0 = fsilu2(d[0]);
        float s1 = fsilu2(d[1]);
        float s2 = fsilu2(d[2]);
        float s3 = fsilu2(d[3]);
        cv[f][0] += s0*wk0.x + s1*wk0.y + s2*wk0.z + s3*wk0.w;
        cv[f][1] += s0*wk1.x + s1*wk1.y + s2*wk1.z + s3*wk1.w;
        cv[f][2] += s0*wk2.x + s1*wk2.y + s2*wk2.z + s3*wk2.w;
      }
    }
    #pragma unroll
    for (int f = 0; f < 4; ++f)
      #pragma unroll
      for (int k = 0; k < 3; ++k) {
        float v = cv[f][k];
        v += __shfl_xor(v, 16, 64);
        v += __shfl_xor(v, 32, 64);
        cv[f][k] = v;
      }
    #pragma unroll
    for (int f = 0; f < 4; ++f) {
      int src = f*16 + l15;
      int eb = __shfl(e, src, 64);
      int jb = t*64 + src;
      if (q0 && jb < E) {
        float* mp = &mlpout[(size_t)eb*3];
        mp[0] = cv[f][0]; mp[1] = cv[f][1]; mp[2] = cv[f][2];
      }
    }
  }
}

// ---------- K5: coord_out, 4 rows per wave (16-lane subgroups) ----------
__global__ __launch_bounds__(256) void k_coord(
    const float* __restrict__ coord, const int* __restrict__ col,
    const int* __restrict__ row_start, const int* __restrict__ eidx,
    const float* __restrict__ aout, const float* __restrict__ mlpout,
    float* __restrict__ cout, int N)
{
  const int tid = threadIdx.x;
  const int wid = tid >> 6, lane = tid & 63;
  const int sub = lane >> 4, sl = lane & 15;
  const int r = blockIdx.x*16 + wid*4 + sub;
  if (r >= N) return;
  const int js = row_start[r], je = row_start[r+1];
  const int deg = je - js;
  float cr[9];
  #pragma unroll
  for (int i = 0; i < 9; ++i) cr[i] = coord[(size_t)r*9 + i];
  float cg[9] = {0.f,0.f,0.f,0.f,0.f,0.f,0.f,0.f,0.f};
  if (deg <= 16) {
    if (sl < deg) {
      int e = eidx[js + sl];
      float a = aout[e];
      int c = col[e];
      float p0 = a*mlpout[(size_t)e*3+0];
      float p1 = a*mlpout[(size_t)e*3+1];
      float p2 = a*mlpout[(size_t)e*3+2];
      #pragma unroll
      for (int d = 0; d < 3; ++d) {
        float c0 = cr[0+d] - coord[(size_t)c*9 + 0+d];
        float c1 = cr[3+d] - coord[(size_t)c*9 + 3+d];
        float c2 = cr[6+d] - coord[(size_t)c*9 + 6+d];
        cg[0+d] = p0*c0; cg[3+d] = p1*c1; cg[6+d] = p2*c2;
      }
    }
  } else {
    for (int j = js + sl; j < je; j += 16) {
      int e = eidx[j];
      float a = aout[e];
      int c = col[e];
      float p0 = a*mlpout[(size_t)e*3+0];
      float p1 = a*mlpout[(size_t)e*3+1];
      float p2 = a*mlpout[(size_t)e*3+2];
      #pragma unroll
      for (int d = 0; d < 3; ++d) {
        cg[0+d] += p0*(cr[0+d] - coord[(size_t)c*9 + 0+d]);
        cg[3+d] += p1*(cr[3+d] - coord[(size_t)c*9 + 3+d]);
        cg[6+d] += p2*(cr[6+d] - coord[(size_t)c*9 + 6+d]);
      }
    }
  }
  #pragma unroll
  for (int i = 0; i < 9; ++i)
    #pragma unroll
    for (int m = 8; m > 0; m >>= 1) cg[i] += __shfl_xor(cg[i], m, 16);
  if (sl == 0) {
    #pragma unroll
    for (int i = 0; i < 9; ++i) {
      float x = fminf(10.f, fmaxf(-10.f, cg[i]));
      cout[(size_t)r*9 + i] = cr[i] + x;
    }
  }
}

extern "C" void kernel_launch(void* const* d_in, const int* in_sizes, int n_in,
                              void* d_out, int out_size, void* d_ws, size_t ws_size,
                              hipStream_t stream)
{
  const float* h     = (const float*)d_in[0];
  const float* coord = (const float*)d_in[1];
  const int* row = (const int*)d_in[2];
  const int* col = (const int*)d_in[3];
  const float* Wq  = (const float*)d_in[4];
  const float* bq  = (const float*)d_in[5];
  const float* Wkv = (const float*)d_in[6];
  const float* bkv = (const float*)d_in[7];
  const float* Wc1 = (const float*)d_in[8];
  const float* Wc2 = (const float*)d_in[9];
  const int N = in_sizes[0] / H;
  const int E = in_sizes[2];
  float* out = (float*)d_out;

  // layout: [qn fp32 | kn bf16] (dead after k_edge_alpha) <- hn bf16 aliases
  char* p = (char*)d_ws;
  float* qn = (float*)p;
  unsigned short* kn = (unsigned short*)(p + (size_t)N*H*4);
  unsigned short* hn = (unsigned short*)p;
  p += (size_t)N*H*8;
  unsigned short* vn = (unsigned short*)p;  p += (size_t)N*H*2;
  float* mlpout = (float*)p;                p += (size_t)E*3*4;
  int* counts_r = (int*)p;                  p += (size_t)N*CPAD*4;   // padded
  int* counts_c = (int*)p;                  p += (size_t)N*CPAD*4;   // padded
  int* cursor_r = (int*)p;                  p += (size_t)N*CPAD*4;   // padded
  int* cursor_c = (int*)p;                  p += (size_t)N*CPAD*4;   // padded
  int* row_start = (int*)p;                 p += (size_t)(N+1)*4;
  int* cstart = (int*)p;                    p += (size_t)(N+1)*4;
  int* eidx = (int*)p;                      p += (size_t)E*4;
  int* eidx2 = (int*)p;                     p += (size_t)E*4;
  uint4* w1f = (uint4*)((((size_t)p) + 15) & ~(size_t)15);
  float* Wr6 = (float*)((char*)w1f + 8192*16);
  uint4* ar6f = (uint4*)((char*)Wr6 + 6*512*4);
  float* w2p  = (float*)((char*)ar6f + 512*16);
  float* qwn  = (float*)((char*)w2p + 1536*4);
  uint4* wcat_hi = (uint4*)((char*)qwn + (size_t)N*6*4);
  uint4* wcat_lo = (uint4*)((char*)wcat_hi + 6144*16);
  const size_t need = (size_t)((char*)wcat_lo + 6144*16 - (char*)d_ws);

  if (ws_size < need) {
    k_sentinel<<<(out_size + 255)/256, 256, 0, stream>>>(out, out_size);
    return;
  }

  float* hout = out;
  float* cout = out + (size_t)N*H;
  float* aout = cout + (size_t)N*9;   // raw ar, then normalized alpha

  k_zero<<<(2*N*CPAD + 255)/256, 256, 0, stream>>>((float*)counts_r, 2*N*CPAD);
  k_prep_w1<<<32, 256, 0, stream>>>(Wc1, w1f);
  k_prep_wcat<<<24, 256, 0, stream>>>(Wq, Wkv, wcat_hi, wcat_lo);
  k_prep_wr6<<<12, 256, 0, stream>>>(Wkv, Wc1, Wr6);
  k_prep_ar6<<<1, 256, 0, stream>>>(Wr6, Wc2, ar6f, w2p);
  k_hist2<<<(E + 255)/256, 256, 0, stream>>>(row, col, counts_r, counts_c, E);
  k_node_mfma<<<(N + 127)/128, 256, 0, stream>>>(h, wcat_hi, wcat_lo, bq, bkv,
                                                 qn, kn, vn, N);
  k_qw<<<(N + 3)/4, 256, 0, stream>>>(qn, Wkv, qwn, N);
  k_scan2<<<2, 1024, 0, stream>>>(counts_r, row_start, cursor_r,
                                  counts_c, cstart, cursor_c, N);
  k_scatter2<<<(E + 255)/256, 256, 0, stream>>>(row, col, cursor_r, eidx,
                                                cursor_c, eidx2, E);
  k_edge_alpha<<<(E + 255)/256, 256, 0, stream>>>(coord, row, col, eidx,
                                                  qn, kn, qwn, aout, E);
  k_row_soft<<<(N + 3)/4, 256, 0, stream>>>(h, coord, col, Wkv, row_start, eidx,
                                            (const unsigned*)vn, aout, hout, N);
  // qn/kn dead from here: hn overwrites their region
  k_node_hn<<<(N + 127)/128, 256, 0, stream>>>((const unsigned*)vn, w1f, hn, N);
  {
    int ntile = (E + 63) >> 6;
    int half = ntile >> 1;
    k_edge_mlp3<<<512, 512, 0, stream>>>(coord, row, col, ar6f, w2p,
                                         hn, eidx2, mlpout, E, 0, half);
    k_edge_mlp3<<<512, 512, 0, stream>>>(coord, row, col, ar6f, w2p,
                                         hn, eidx2, mlpout, E, half, ntile);
  }
  k_coord<<<(N + 15)/16, 256, 0, stream>>>(coord, col, row_start, eidx, aout,
                                           mlpout, cout, N);
}

// Round 14
// 614.024 us; speedup vs baseline: 1.1238x; 1.1238x over previous
//
#include <hip/hip_runtime.h>

#define H 128
#define KV 256
#define CPAD 16   // counters padded to one per 64B line (R12: line-contention fix)

typedef short bf16x8 __attribute__((ext_vector_type(8)));
typedef float f32x4 __attribute__((ext_vector_type(4)));
union FragU { uint4 u; bf16x8 s; };

#define LOG2E 1.44269504088896f
#define LN2   0.69314718055995f

__device__ __forceinline__ float bf2f(unsigned short u) {
  return __uint_as_float(((unsigned)u) << 16);
}
__device__ __forceinline__ unsigned short f2bf(float f) {
  unsigned b = __float_as_uint(f);
  b += 0x7FFFu + ((b >> 16) & 1u);   // round-to-nearest-even
  return (unsigned short)(b >> 16);
}
// fast silu: x * rcp(1+exp(-x)); v_rcp_f32 ~1ulp, well inside absmax budget.
__device__ __forceinline__ float fsilu(float x) {
  return x * __builtin_amdgcn_rcpf(1.f + __expf(-x));
}
// raw v_exp_f32: D = 2^S0 (ISA-doc semantics)
__device__ __forceinline__ float fexp2(float x) {
  float r;
  asm("v_exp_f32 %0, %1" : "=v"(r) : "v"(x));
  return r;
}
// silu in log2-domain: input y = x*log2e; returns silu(x)*log2e
// (the ln2 is pre-folded into the Wc2 table).
__device__ __forceinline__ float fsilu2(float y) {
  return y * __builtin_amdgcn_rcpf(1.f + fexp2(-y));
}
// rad6 = unique entries of the symmetric radial matrix [00,11,22,01,02,12]
__device__ __forceinline__ void rad6_from_cd(const float cd[9], float r6[6]) {
  r6[0] = cd[0]*cd[0] + cd[1]*cd[1] + cd[2]*cd[2];
  r6[1] = cd[3]*cd[3] + cd[4]*cd[4] + cd[5]*cd[5];
  r6[2] = cd[6]*cd[6] + cd[7]*cd[7] + cd[8]*cd[8];
  r6[3] = cd[0]*cd[3] + cd[1]*cd[4] + cd[2]*cd[5];
  r6[4] = cd[0]*cd[6] + cd[1]*cd[7] + cd[2]*cd[8];
  r6[5] = cd[3]*cd[6] + cd[4]*cd[7] + cd[5]*cd[8];
}
__constant__ int c_pa[6] = {0,4,8,1,2,5};
__constant__ int c_pb[6] = {0,0,0,3,6,7};

__global__ __launch_bounds__(256) void k_zero(float* __restrict__ p, int n) {
  int i = blockIdx.x * 256 + threadIdx.x;
  if (i < n) p[i] = 0.f;
}
__global__ __launch_bounds__(256) void k_sentinel(float* __restrict__ out, int n) {
  int i = blockIdx.x * 256 + threadIdx.x;
  if (i < n) out[i] = 1000.0f;
}

// pack Wc1 (128x512 fp32) into bf16 fragment order (verified R5-R10).
// Pre-scaled by log2e (hn arrives in log2-domain for fsilu2; hn feeds ONLY
// k_edge_mlp3).
__global__ __launch_bounds__(256) void k_prep_w1(const float* __restrict__ Wc1,
                                                 uint4* __restrict__ w1f) {
  int t = blockIdx.x*256 + threadIdx.x;    // 8192 total
  int g = t >> 6, lane = t & 63;
  int q = g >> 5, kk = (g >> 3) & 3, mt = g & 7;
  int o = q*128 + mt*16 + (lane & 15);
  int kbase = kk*32 + (lane >> 4)*8;
  unsigned s[8];
  #pragma unroll
  for (int j = 0; j < 8; ++j) s[j] = f2bf(Wc1[(kbase+j)*512 + o] * LOG2E);
  uint4 u;
  u.x = s[0] | (s[1]<<16); u.y = s[2] | (s[3]<<16);
  u.z = s[4] | (s[5]<<16); u.w = s[6] | (s[7]<<16);
  w1f[g*64 + lane] = u;
}

// pack Wcat = [Wq | Wkv-even(k) | Wkv-odd(v)] (128 x 384) into bf16 hi/lo
// MFMA A-frags (bf16x3 trick: w = hi + lo, each bf16). g = (q*4+kk)*8+mt.
__global__ __launch_bounds__(256) void k_prep_wcat(
    const float* __restrict__ Wq, const float* __restrict__ Wkv,
    uint4* __restrict__ wcat_hi, uint4* __restrict__ wcat_lo)
{
  int t = blockIdx.x*256 + threadIdx.x;   // 6144 total
  if (t >= 96*64) return;
  int g = t >> 6, lane = t & 63;
  int mt = g & 7, kk = (g >> 3) & 3, q = g >> 5;
  int oo = mt*16 + (lane & 15);       // 0..127 within section
  int kbase = kk*32 + (lane >> 4)*8;
  unsigned shi[8], slo[8];
  #pragma unroll
  for (int j = 0; j < 8; ++j) {
    int k = kbase + j;
    float w;
    if (q == 0)      w = Wq[k*H + oo];
    else if (q == 1) w = Wkv[(9 + k)*KV + 2*oo];
    else             w = Wkv[(9 + k)*KV + 2*oo + 1];
    unsigned hi = f2bf(w);
    float lo = w - bf2f((unsigned short)hi);
    shi[j] = hi; slo[j] = f2bf(lo);
  }
  uint4 uh, ul;
  uh.x = shi[0]|(shi[1]<<16); uh.y = shi[2]|(shi[3]<<16);
  uh.z = shi[4]|(shi[5]<<16); uh.w = shi[6]|(shi[7]<<16);
  ul.x = slo[0]|(slo[1]<<16); ul.y = slo[2]|(slo[3]<<16);
  ul.z = slo[4]|(slo[5]<<16); ul.w = slo[6]|(slo[7]<<16);
  wcat_hi[g*64 + lane] = uh;
  wcat_lo[g*64 + lane] = ul;
}

// Wr6[6][512] = sym-folded (Wvo @ Wc1)
__global__ __launch_bounds__(256) void k_prep_wr6(const float* __restrict__ Wkv,
                                                  const float* __restrict__ Wc1,
                                                  float* __restrict__ Wr6) {
  int idx = blockIdx.x*256 + threadIdx.x;   // 3072
  if (idx >= 6*512) return;
  int d = idx >> 9, o = idx & 511;
  float s = 0.f;
  for (int k = 0; k < 128; ++k) {
    float w = Wkv[c_pa[d]*KV + 2*k + 1];
    if (d >= 3) w += Wkv[c_pb[d]*KV + 2*k + 1];
    s += w * Wc1[k*512 + o];
  }
  Wr6[d*512 + o] = s;
}

// pack Wr6 into bf16 MFMA A-frags (scaled by log2e, matching hn's domain)
// and Wc2 into quad-broadcast float4 table (scaled by ln2 to undo it).
__global__ __launch_bounds__(256) void k_prep_ar6(
    const float* __restrict__ Wr6, const float* __restrict__ Wc2,
    uint4* __restrict__ ar6f, float* __restrict__ w2p)
{
  int t = threadIdx.x;
  for (int i = t; i < 512; i += 256) {
    int ch = i;
    unsigned b0 = (unsigned)f2bf(Wr6[0*512+ch]*LOG2E) | ((unsigned)f2bf(Wr6[1*512+ch]*LOG2E)<<16);
    unsigned b1 = (unsigned)f2bf(Wr6[2*512+ch]*LOG2E) | ((unsigned)f2bf(Wr6[3*512+ch]*LOG2E)<<16);
    unsigned b2 = (unsigned)f2bf(Wr6[4*512+ch]*LOG2E) | ((unsigned)f2bf(Wr6[5*512+ch]*LOG2E)<<16);
    ar6f[i] = make_uint4(b0, b1, b2, 0u);
  }
  for (int i = t; i < 1536; i += 256) {
    int i4 = i & 3, rest = i >> 2;
    int k = rest % 3, g = rest / 3;
    int ch = (g >> 2)*16 + (g & 3)*4 + i4;
    w2p[i] = Wc2[ch*3 + k] * LN2;
  }
}

// ---------- dual counting sort (row + col) ----------
// Counters padded 1-per-64B-line (R13: helped scatter/hist ~20us).
__global__ __launch_bounds__(256) void k_hist2(const int* __restrict__ row,
                                               const int* __restrict__ col,
                                               int* __restrict__ cr,
                                               int* __restrict__ cc, int E) {
  int e = blockIdx.x*256 + threadIdx.x;
  if (e >= E) return;
  atomicAdd(&cr[(size_t)row[e]*CPAD], 1);
  atomicAdd(&cc[(size_t)col[e]*CPAD], 1);
}

// ---------- R13: hierarchical 3-phase scan (replaces the 2-block serial
// k_scan2 that hit 87us at 0.34% occupancy with strided CPAD reads) ----------
// Phase A: each block scans 1024 counters (4/thread), writes local exclusive
// starts (dense) + per-block sum.
__global__ __launch_bounds__(256) void k_scan_local(
    const int* __restrict__ cr, const int* __restrict__ cc,
    int* __restrict__ rstart, int* __restrict__ cstart,
    int* __restrict__ bsum, int n, int nb)
{
  int arr = blockIdx.x / nb;
  int b = blockIdx.x - arr*nb;
  const int* counts = arr ? cc : cr;
  int* start = arr ? cstart : rstart;
  __shared__ int wsum[4];
  const int tid = threadIdx.x, lane = tid & 63, wid = tid >> 6;
  int i0 = b*1024 + tid*4;
  int v0 = (i0+0 < n) ? counts[(size_t)(i0+0)*CPAD] : 0;
  int v1 = (i0+1 < n) ? counts[(size_t)(i0+1)*CPAD] : 0;
  int v2 = (i0+2 < n) ? counts[(size_t)(i0+2)*CPAD] : 0;
  int v3 = (i0+3 < n) ? counts[(size_t)(i0+3)*CPAD] : 0;
  int t = v0 + v1 + v2 + v3;
  int s = t;
  #pragma unroll
  for (int off = 1; off < 64; off <<= 1) {
    int u = __shfl_up(s, off, 64);
    if (lane >= off) s += u;
  }
  if (lane == 63) wsum[wid] = s;
  __syncthreads();
  int wexcl = 0;
  #pragma unroll
  for (int w = 0; w < 3; ++w) if (wid > w) wexcl += wsum[w];
  int texcl = wexcl + (s - t);
  if (i0+0 < n) start[i0+0] = texcl;
  if (i0+1 < n) start[i0+1] = texcl + v0;
  if (i0+2 < n) start[i0+2] = texcl + v0 + v1;
  if (i0+3 < n) start[i0+3] = texcl + v0 + v1 + v2;
  if (tid == 255) bsum[blockIdx.x] = wexcl + s;
}

// Phase B: one block, wave 0 scans row block-sums, wave 1 col block-sums
// (chunked with carry; handles any nb). Writes start[n] totals.
__global__ __launch_bounds__(128) void k_scan_mid(
    const int* __restrict__ bsum, int* __restrict__ boff,
    int* __restrict__ rstart, int* __restrict__ cstart, int n, int nb)
{
  int arr = threadIdx.x >> 6, lane = threadIdx.x & 63;
  int carry = 0;
  for (int base = 0; base < nb; base += 64) {
    int i = base + lane;
    int v = (i < nb) ? bsum[arr*nb + i] : 0;
    int s = v;
    #pragma unroll
    for (int off = 1; off < 64; off <<= 1) {
      int u = __shfl_up(s, off, 64);
      if (lane >= off) s += u;
    }
    if (i < nb) boff[arr*nb + i] = carry + s - v;
    carry += __shfl(s, 63, 64);
  }
  if (lane == 0) {
    if (arr == 0) rstart[n] = carry; else cstart[n] = carry;
  }
}

// Phase C: add block offsets; write dense start + padded cursor.
__global__ __launch_bounds__(256) void k_scan_add(
    int* __restrict__ rstart, int* __restrict__ rcur,
    int* __restrict__ cstart, int* __restrict__ ccur,
    const int* __restrict__ boff, int n, int nb)
{
  int idx = blockIdx.x*256 + threadIdx.x;
  if (idx >= 2*n) return;
  int arr = (idx >= n) ? 1 : 0;
  int i = arr ? (idx - n) : idx;
  int b = i >> 10;
  int off = boff[arr*nb + b];
  int* start = arr ? cstart : rstart;
  int* cur = arr ? ccur : rcur;
  int sv = start[i] + off;
  start[i] = sv;
  cur[(size_t)i*CPAD] = sv;
}

__global__ __launch_bounds__(256) void k_scatter2(
    const int* __restrict__ row, const int* __restrict__ col,
    int* __restrict__ rcur, int* __restrict__ eidx,
    int* __restrict__ ccur, int* __restrict__ eidx2, int E) {
  int e = blockIdx.x*256 + threadIdx.x;
  if (e >= E) return;
  int pos = atomicAdd(&rcur[(size_t)row[e]*CPAD], 1);
  eidx[pos] = e;
  int pos2 = atomicAdd(&ccur[(size_t)col[e]*CPAD], 1);
  eidx2[pos2] = e;
}

// ---------- K1: node projection as bf16x3 MFMA GEMM (verified R4) ----------
// kn stored bf16 (R12, verified: halves alpha gather traffic).
__global__ __launch_bounds__(256) void k_node_mfma(
    const float* __restrict__ h, const uint4* __restrict__ wcat_hi,
    const uint4* __restrict__ wcat_lo, const float* __restrict__ bq,
    const float* __restrict__ bkv, float* __restrict__ qn,
    unsigned short* __restrict__ kn, unsigned short* __restrict__ vn, int N)
{
  __shared__ unsigned vhi[128*64];
  __shared__ unsigned vlo[128*64];
  const int tid = threadIdx.x;
  const int wid = tid >> 6, lane = tid & 63;
  const int quad = lane >> 4, colc = lane & 15;
  const int n0 = blockIdx.x * 128;
  for (int i = 0; i < 32; ++i) {
    int el = i*4 + wid;
    int c = n0 + el; if (c >= N) c = N - 1;
    float2 hv = *((const float2*)(h + (size_t)c*H + 2*lane));
    unsigned h0 = f2bf(hv.x), h1 = f2bf(hv.y);
    float l0 = hv.x - bf2f((unsigned short)h0);
    float l1 = hv.y - bf2f((unsigned short)h1);
    int sw = el*64 + (((lane>>2) ^ (el&15))<<2) + (lane&3);
    vhi[sw] = h0 | (h1<<16);
    vlo[sw] = (unsigned)f2bf(l0) | ((unsigned)f2bf(l1)<<16);
  }
  __syncthreads();
  const int ntbase = wid*32;
  for (int q = 0; q < 3; ++q) {
    f32x4 acc[8][2];
    #pragma unroll
    for (int mt = 0; mt < 8; ++mt)
      #pragma unroll
      for (int nt = 0; nt < 2; ++nt) acc[mt][nt] = (f32x4){0.f,0.f,0.f,0.f};
    #pragma unroll
    for (int kk = 0; kk < 4; ++kk) {
      FragU bhi[2], blo[2];
      #pragma unroll
      for (int nt = 0; nt < 2; ++nt) {
        int rrow = ntbase + nt*16 + colc;
        int ad = rrow*64 + (((kk*4 + quad) ^ (rrow&15))<<2);
        bhi[nt].u = *((const uint4*)&vhi[ad]);
        blo[nt].u = *((const uint4*)&vlo[ad]);
      }
      #pragma unroll
      for (int mt = 0; mt < 8; ++mt) {
        FragU ahi, alo;
        int gidx = (((q*4+kk)*8+mt)<<6) + lane;
        ahi.u = wcat_hi[gidx];
        alo.u = wcat_lo[gidx];
        #pragma unroll
        for (int nt = 0; nt < 2; ++nt) {
          acc[mt][nt] = __builtin_amdgcn_mfma_f32_16x16x32_bf16(
              ahi.s, bhi[nt].s, acc[mt][nt], 0, 0, 0);
          acc[mt][nt] = __builtin_amdgcn_mfma_f32_16x16x32_bf16(
              ahi.s, blo[nt].s, acc[mt][nt], 0, 0, 0);
          acc[mt][nt] = __builtin_amdgcn_mfma_f32_16x16x32_bf16(
              alo.s, bhi[nt].s, acc[mt][nt], 0, 0, 0);
        }
      }
    }
    #pragma unroll
    for (int mt = 0; mt < 8; ++mt)
      #pragma unroll
      for (int nt = 0; nt < 2; ++nt) {
        int node = n0 + ntbase + nt*16 + colc;
        if (node >= N) continue;
        int chq = mt*16 + quad*4;     // 0..127 within section
        if (q == 0) {
          float4 b = *((const float4*)(bq + chq));
          float4 o;
          o.x = acc[mt][nt][0] + b.x; o.y = acc[mt][nt][1] + b.y;
          o.z = acc[mt][nt][2] + b.z; o.w = acc[mt][nt][3] + b.w;
          *((float4*)(qn + (size_t)node*H + chq)) = o;
        } else if (q == 1) {
          unsigned s0 = f2bf(acc[mt][nt][0] + bkv[2*(chq+0)]);
          unsigned s1 = f2bf(acc[mt][nt][1] + bkv[2*(chq+1)]);
          unsigned s2 = f2bf(acc[mt][nt][2] + bkv[2*(chq+2)]);
          unsigned s3 = f2bf(acc[mt][nt][3] + bkv[2*(chq+3)]);
          *((uint2*)(kn + (size_t)node*H + chq)) =
              make_uint2(s0 | (s1<<16), s2 | (s3<<16));
        } else {
          unsigned s0 = f2bf(acc[mt][nt][0] + bkv[2*(chq+0)+1]);
          unsigned s1 = f2bf(acc[mt][nt][1] + bkv[2*(chq+1)+1]);
          unsigned s2 = f2bf(acc[mt][nt][2] + bkv[2*(chq+2)+1]);
          unsigned s3 = f2bf(acc[mt][nt][3] + bkv[2*(chq+3)+1]);
          *((uint2*)(vn + (size_t)node*H + chq)) =
              make_uint2(s0 | (s1<<16), s2 | (s3<<16));
        }
      }
  }
}

// ---------- K2pre: qwn[n][6] = q_n @ Wke6^T ----------
__global__ __launch_bounds__(256) void k_qw(
    const float* __restrict__ qn, const float* __restrict__ Wkv,
    float* __restrict__ qwn, int N)
{
  __shared__ float wke6[6*128];
  const int tid = threadIdx.x;
  for (int idx = tid; idx < 6*128; idx += 256) {
    int d = idx >> 7, j = idx & 127;
    float we = Wkv[c_pa[d]*KV + 2*j];
    if (d >= 3) we += Wkv[c_pb[d]*KV + 2*j];
    wke6[idx] = we;
  }
  __syncthreads();
  const int wid = tid >> 6, lane = tid & 63;
  const int n = blockIdx.x*4 + wid;
  if (n >= N) return;
  float q0 = qn[(size_t)n*H + lane];
  float q1 = qn[(size_t)n*H + 64 + lane];
  #pragma unroll
  for (int d = 0; d < 6; ++d) {
    float p = q0*wke6[d*128 + lane] + q1*wke6[d*128 + 64 + lane];
    #pragma unroll
    for (int m = 32; m > 0; m >>= 1) p += __shfl_xor(p, m, 64);
    if (lane == 0) qwn[(size_t)n*6 + d] = p;
  }
}

// ---------- K2a: edge-parallel raw alpha. lane = edge. kn in bf16. ----------
__global__ __launch_bounds__(256) void k_edge_alpha(
    const float* __restrict__ coord, const int* __restrict__ row,
    const int* __restrict__ col, const int* __restrict__ eidx,
    const float* __restrict__ qn, const unsigned short* __restrict__ knb,
    const float* __restrict__ qwn, float* __restrict__ aout, int E)
{
  int j = blockIdx.x*256 + threadIdx.x;
  if (j >= E) return;
  int e = eidx[j];
  int r = row[e], c = col[e];
  const float4* qp = (const float4*)(qn + (size_t)r*H);
  const uint4* kp = (const uint4*)(knb + (size_t)c*H);
  float d0 = 0.f, d1 = 0.f, d2 = 0.f, d3 = 0.f;
  #pragma unroll 4
  for (int i = 0; i < 16; ++i) {
    uint4 kv = kp[i];
    float4 q0 = qp[2*i], q1 = qp[2*i+1];
    d0 += q0.x*__uint_as_float(kv.x << 16) + q0.y*__uint_as_float(kv.x & 0xffff0000u);
    d1 += q0.z*__uint_as_float(kv.y << 16) + q0.w*__uint_as_float(kv.y & 0xffff0000u);
    d2 += q1.x*__uint_as_float(kv.z << 16) + q1.y*__uint_as_float(kv.z & 0xffff0000u);
    d3 += q1.z*__uint_as_float(kv.w << 16) + q1.w*__uint_as_float(kv.w & 0xffff0000u);
  }
  float cd[9], r6[6];
  #pragma unroll
  for (int i = 0; i < 9; ++i)
    cd[i] = coord[(size_t)r*9 + i] - coord[(size_t)c*9 + i];
  rad6_from_cd(cd, r6);
  float ar = (d0 + d1) + (d2 + d3);
  #pragma unroll
  for (int d = 0; d < 6; ++d) ar += r6[d]*qwn[(size_t)r*6 + d];
  aout[e] = ar;
}

// ---------- K2b: exact per-row softmax + h_out ----------
__global__ __launch_bounds__(256) void k_row_soft(
    const float* __restrict__ h, const float* __restrict__ coord,
    const int* __restrict__ col, const float* __restrict__ Wkv,
    const int* __restrict__ row_start, const int* __restrict__ eidx,
    const unsigned* __restrict__ vnu, float* __restrict__ aout,
    float* __restrict__ hout, int N)
{
  __shared__ float wvo6[6*128];
  __shared__ float ws[4][64];
  __shared__ int   cs[4][64];
  const int tid = threadIdx.x;
  for (int idx = tid; idx < 6*128; idx += 256) {
    int d = idx >> 7, jj = idx & 127;
    float wo = Wkv[c_pa[d]*KV + 2*jj + 1];
    if (d >= 3) wo += Wkv[c_pb[d]*KV + 2*jj + 1];
    wvo6[idx] = wo;
  }
  __syncthreads();
  const int wid = tid >> 6, lane = tid & 63;
  const int r = blockIdx.x*4 + wid;
  if (r >= N) return;
  const int js = row_start[r], je = row_start[r+1];
  const int deg = je - js;
  float crd[9];
  #pragma unroll
  for (int i = 0; i < 9; ++i) crd[i] = coord[(size_t)r*9 + i];

  float t6s[6];
  float mn, invl;
  const bool big = (deg > 64);
  if (!big) {
    int e = 0, c = 0;
    float ar = -1e30f;
    float r6[6] = {0.f,0.f,0.f,0.f,0.f,0.f};
    if (lane < deg) {
      e = eidx[js + lane];
      ar = aout[e];
      c = col[e];
      float cd[9];
      #pragma unroll
      for (int i = 0; i < 9; ++i) cd[i] = crd[i] - coord[(size_t)c*9 + i];
      rad6_from_cd(cd, r6);
    }
    float mx = ar;
    #pragma unroll
    for (int m = 32; m > 0; m >>= 1) mx = fmaxf(mx, __shfl_xor(mx, m, 64));
    mn = mx;
    float w = (lane < deg) ? __expf(ar - mn) : 0.f;
    float lw = w;
    #pragma unroll
    for (int m = 32; m > 0; m >>= 1) lw += __shfl_xor(lw, m, 64);
    invl = (deg > 0) ? 1.f/lw : 0.f;
    #pragma unroll
    for (int d = 0; d < 6; ++d) {
      float v = w*r6[d];
      #pragma unroll
      for (int m = 32; m > 0; m >>= 1) v += __shfl_xor(v, m, 64);
      t6s[d] = v;
    }
    ws[wid][lane] = w;
    cs[wid][lane] = c;
    if (lane < deg) aout[e] = w*invl;
  } else {
    float mx = -1e30f;
    for (int j2 = js + lane; j2 < je; j2 += 64)
      mx = fmaxf(mx, aout[eidx[j2]]);
    #pragma unroll
    for (int m = 32; m > 0; m >>= 1) mx = fmaxf(mx, __shfl_xor(mx, m, 64));
    mn = mx;
    float lp = 0.f;
    float t6p[6] = {0.f,0.f,0.f,0.f,0.f,0.f};
    for (int j2 = js + lane; j2 < je; j2 += 64) {
      int e = eidx[j2];
      float ar = aout[e];
      float w = __expf(ar - mn);
      lp += w;
      int c = col[e];
      float cd[9], r6[6];
      #pragma unroll
      for (int i = 0; i < 9; ++i) cd[i] = crd[i] - coord[(size_t)c*9 + i];
      rad6_from_cd(cd, r6);
      #pragma unroll
      for (int d = 0; d < 6; ++d) t6p[d] += w*r6[d];
    }
    #pragma unroll
    for (int m = 32; m > 0; m >>= 1) lp += __shfl_xor(lp, m, 64);
    invl = (deg > 0) ? 1.f/lp : 0.f;
    #pragma unroll
    for (int d = 0; d < 6; ++d) {
      float v = t6p[d];
      #pragma unroll
      for (int m = 32; m > 0; m >>= 1) v += __shfl_xor(v, m, 64);
      t6s[d] = v;
    }
  }
  float acc0 = 0.f, acc1 = 0.f;
  if (!big) {
    #pragma unroll 4
    for (int t = 0; t < deg; ++t) {
      float w = ws[wid][t];
      int c = cs[wid][t];
      unsigned v = vnu[(size_t)c*64 + lane];
      acc0 += w*__uint_as_float(v << 16);
      acc1 += w*__uint_as_float(v & 0xffff0000u);
    }
  } else {
    for (int t = js; t < je; ++t) {
      int e = eidx[t];
      float ar = aout[e];
      float w = __expf(ar - mn);
      int c = col[e];
      unsigned v = vnu[(size_t)c*64 + lane];
      acc0 += w*__uint_as_float(v << 16);
      acc1 += w*__uint_as_float(v & 0xffff0000u);
    }
    for (int j2 = js + lane; j2 < je; j2 += 64) {
      int e = eidx[j2];
      aout[e] = __expf(aout[e] - mn)*invl;
    }
  }
  float o0 = acc0, o1 = acc1;
  #pragma unroll
  for (int d = 0; d < 6; ++d) {
    o0 += t6s[d]*wvo6[d*128 + 2*lane];
    o1 += t6s[d]*wvo6[d*128 + 2*lane + 1];
  }
  hout[(size_t)r*H + 2*lane]     = h[(size_t)r*H + 2*lane]     + o0*invl;
  hout[(size_t)r*H + 2*lane + 1] = h[(size_t)r*H + 2*lane + 1] + o1*invl;
}

// ---------- K4a: hn[N][512] bf16 = vn @ (Wc1*log2e) (node MFMA GEMM) ----------
__global__ __launch_bounds__(256) void k_node_hn(
    const unsigned* __restrict__ vnu, const uint4* __restrict__ w1f,
    unsigned short* __restrict__ hn, int N)
{
  __shared__ unsigned vt[128*64];
  __shared__ unsigned short hno[128*128];
  const int tid = threadIdx.x;
  const int wid = tid >> 6, lane = tid & 63;
  const int quad = lane >> 4, colc = lane & 15;
  const int n0 = blockIdx.x * 128;
  for (int i = 0; i < 32; ++i) {
    int el = i*4 + wid;
    int c = n0 + el; if (c >= N) c = N - 1;
    unsigned pk = vnu[(size_t)c*64 + lane];
    vt[el*64 + (((lane>>2) ^ (el&15))<<2) + (lane&3)] = pk;
  }
  __syncthreads();
  const int ntbase = wid*32;
  for (int q = 0; q < 4; ++q) {
    f32x4 acc[8][2];
    #pragma unroll
    for (int mt = 0; mt < 8; ++mt)
      #pragma unroll
      for (int nt = 0; nt < 2; ++nt) acc[mt][nt] = (f32x4){0.f,0.f,0.f,0.f};
    #pragma unroll
    for (int kk = 0; kk < 4; ++kk) {
      FragU bfr[2];
      #pragma unroll
      for (int nt = 0; nt < 2; ++nt) {
        int rrow = ntbase + nt*16 + colc;
        int chunk = kk*4 + quad;
        bfr[nt].u = *((const uint4*)&vt[rrow*64 + ((chunk ^ (rrow&15))<<2)]);
      }
      #pragma unroll
      for (int mt = 0; mt < 8; ++mt) {
        FragU afr;
        afr.u = w1f[(((q*4+kk)*8+mt)<<6) + lane];
        #pragma unroll
        for (int nt = 0; nt < 2; ++nt)
          acc[mt][nt] = __builtin_amdgcn_mfma_f32_16x16x32_bf16(
              afr.s, bfr[nt].s, acc[mt][nt], 0, 0, 0);
      }
    }
    #pragma unroll
    for (int mt = 0; mt < 8; ++mt)
      #pragma unroll
      for (int nt = 0; nt < 2; ++nt) {
        int node = ntbase + nt*16 + colc;
        int o = mt*16 + quad*4;
        unsigned lo = (unsigned)f2bf(acc[mt][nt][0]) | ((unsigned)f2bf(acc[mt][nt][1]) << 16);
        unsigned hi = (unsigned)f2bf(acc[mt][nt][2]) | ((unsigned)f2bf(acc[mt][nt][3]) << 16);
        *((uint2*)&hno[node*128 + o]) = make_uint2(lo, hi);
      }
    __syncthreads();
    const uint4* hns = (const uint4*)hno;
    #pragma unroll
    for (int it = 0; it < 8; ++it) {
      int u = it*256 + tid;
      int node = u >> 4, within = u & 15;
      int gn = n0 + node;
      if (gn < N) ((uint4*)hn)[(size_t)gn*64 + q*16 + within] = hns[node*16 + within];
    }
    __syncthreads();
  }
}

// ---------- K4b: mlpout via MFMA + fsilu2, [tbase,tend) range split ----------
__global__ __launch_bounds__(512) void k_edge_mlp3(
    const float* __restrict__ coord, const int* __restrict__ row,
    const int* __restrict__ col, const uint4* __restrict__ ar6f,
    const float* __restrict__ w2p, const unsigned short* __restrict__ hn,
    const int* __restrict__ eidx2, float* __restrict__ mlpout, int E,
    int tbase, int tend)
{
  __shared__ uint4 a8[512];
  __shared__ float4 w2s[384];
  const int tid = threadIdx.x;
  {
    const uint4* s4 = (const uint4*)w2p;
    for (int i = tid; i < 512; i += 512) a8[i] = ar6f[i];
    if (tid < 384) w2s[tid] = ((const float4*)s4)[tid];
  }
  __syncthreads();
  const int wid = tid >> 6, lane = tid & 63;
  const int l15 = lane & 15, quad = lane >> 4;
  const bool q0 = (quad == 0);

  int gw = blockIdx.x*8 + wid;
  int nw = gridDim.x*8;
  for (int t = tbase + gw; t < tend; t += nw) {
    int j = t*64 + lane;
    int jc = (j < E) ? j : (E - 1);
    int e = eidx2[jc];
    int c = col[e];
    int r = row[e];
    float cd[9], r6[6];
    #pragma unroll
    for (int i = 0; i < 9; ++i)
      cd[i] = coord[(size_t)r*9 + i] - coord[(size_t)c*9 + i];
    rad6_from_cd(cd, r6);
    unsigned pw0 = (unsigned)f2bf(r6[0]) | ((unsigned)f2bf(r6[1]) << 16);
    unsigned pw1 = (unsigned)f2bf(r6[2]) | ((unsigned)f2bf(r6[3]) << 16);
    unsigned pw2 = (unsigned)f2bf(r6[4]) | ((unsigned)f2bf(r6[5]) << 16);
    FragU bfr[4];
    const unsigned short* hb[4];
    #pragma unroll
    for (int f = 0; f < 4; ++f) {
      int src = f*16 + l15;
      unsigned w0 = __shfl(pw0, src, 64);
      unsigned w1 = __shfl(pw1, src, 64);
      unsigned w2_ = __shfl(pw2, src, 64);
      bfr[f].u = make_uint4(q0 ? w0 : 0u, q0 ? w1 : 0u, q0 ? w2_ : 0u, 0u);
      int nb = __shfl(c, src, 64);
      hb[f] = hn + (size_t)nb*512 + quad*4;
    }
    float cv[4][3];
    #pragma unroll
    for (int f = 0; f < 4; ++f) { cv[f][0]=0.f; cv[f][1]=0.f; cv[f][2]=0.f; }

    #pragma unroll 2
    for (int m = 0; m < 32; ++m) {
      uint4 av = a8[m*16 + l15];
      FragU afr;
      afr.u = make_uint4(q0 ? av.x : 0u, q0 ? av.y : 0u, q0 ? av.z : 0u, 0u);
      float4 wk0 = w2s[(m*4 + quad)*3 + 0];
      float4 wk1 = w2s[(m*4 + quad)*3 + 1];
      float4 wk2 = w2s[(m*4 + quad)*3 + 2];
      #pragma unroll
      for (int f = 0; f < 4; ++f) {
        uint2 hv = *((const uint2*)(hb[f] + m*16));
        f32x4 cin;
        cin[0] = __uint_as_float(hv.x << 16);
        cin[1] = __uint_as_float(hv.x & 0xffff0000u);
        cin[2] = __uint_as_float(hv.y << 16);
        cin[3] = __uint_as_float(hv.y & 0xffff0000u);
        f32x4 d = __builtin_amdgcn_mfma_f32_16x16x32_bf16(
            afr.s, bfr[f].s, cin, 0, 0, 0);
        float s0 = fsilu2(d[0]);
        float s1 = fsilu2(d[1]);
        float s2 = fsilu2(d[2]);
        float s3 = fsilu2(d[3]);
        cv[f][0] += s0*wk0.x + s1*wk0.y + s2*wk0.z + s3*wk0.w;
        cv[f][1] += s0*wk1.x + s1*wk1.y + s2*wk1.z + s3*wk1.w;
        cv[f][2] += s0*wk2.x + s1*wk2.y + s2*wk2.z + s3*wk2.w;
      }
    }
    #pragma unroll
    for (int f = 0; f < 4; ++f)
      #pragma unroll
      for (int k = 0; k < 3; ++k) {
        float v = cv[f][k];
        v += __shfl_xor(v, 16, 64);
        v += __shfl_xor(v, 32, 64);
        cv[f][k] = v;
      }
    #pragma unroll
    for (int f = 0; f < 4; ++f) {
      int src = f*16 + l15;
      int eb = __shfl(e, src, 64);
      int jb = t*64 + src;
      if (q0 && jb < E) {
        float* mp = &mlpout[(size_t)eb*3];
        mp[0] = cv[f][0]; mp[1] = cv[f][1]; mp[2] = cv[f][2];
      }
    }
  }
}

// ---------- K5: coord_out, 4 rows per wave (16-lane subgroups) ----------
__global__ __launch_bounds__(256) void k_coord(
    const float* __restrict__ coord, const int* __restrict__ col,
    const int* __restrict__ row_start, const int* __restrict__ eidx,
    const float* __restrict__ aout, const float* __restrict__ mlpout,
    float* __restrict__ cout, int N)
{
  const int tid = threadIdx.x;
  const int wid = tid >> 6, lane = tid & 63;
  const int sub = lane >> 4, sl = lane & 15;
  const int r = blockIdx.x*16 + wid*4 + sub;
  if (r >= N) return;
  const int js = row_start[r], je = row_start[r+1];
  const int deg = je - js;
  float cr[9];
  #pragma unroll
  for (int i = 0; i < 9; ++i) cr[i] = coord[(size_t)r*9 + i];
  float cg[9] = {0.f,0.f,0.f,0.f,0.f,0.f,0.f,0.f,0.f};
  if (deg <= 16) {
    if (sl < deg) {
      int e = eidx[js + sl];
      float a = aout[e];
      int c = col[e];
      float p0 = a*mlpout[(size_t)e*3+0];
      float p1 = a*mlpout[(size_t)e*3+1];
      float p2 = a*mlpout[(size_t)e*3+2];
      #pragma unroll
      for (int d = 0; d < 3; ++d) {
        float c0 = cr[0+d] - coord[(size_t)c*9 + 0+d];
        float c1 = cr[3+d] - coord[(size_t)c*9 + 3+d];
        float c2 = cr[6+d] - coord[(size_t)c*9 + 6+d];
        cg[0+d] = p0*c0; cg[3+d] = p1*c1; cg[6+d] = p2*c2;
      }
    }
  } else {
    for (int j = js + sl; j < je; j += 16) {
      int e = eidx[j];
      float a = aout[e];
      int c = col[e];
      float p0 = a*mlpout[(size_t)e*3+0];
      float p1 = a*mlpout[(size_t)e*3+1];
      float p2 = a*mlpout[(size_t)e*3+2];
      #pragma unroll
      for (int d = 0; d < 3; ++d) {
        cg[0+d] += p0*(cr[0+d] - coord[(size_t)c*9 + 0+d]);
        cg[3+d] += p1*(cr[3+d] - coord[(size_t)c*9 + 3+d]);
        cg[6+d] += p2*(cr[6+d] - coord[(size_t)c*9 + 6+d]);
      }
    }
  }
  #pragma unroll
  for (int i = 0; i < 9; ++i)
    #pragma unroll
    for (int m = 8; m > 0; m >>= 1) cg[i] += __shfl_xor(cg[i], m, 16);
  if (sl == 0) {
    #pragma unroll
    for (int i = 0; i < 9; ++i) {
      float x = fminf(10.f, fmaxf(-10.f, cg[i]));
      cout[(size_t)r*9 + i] = cr[i] + x;
    }
  }
}

extern "C" void kernel_launch(void* const* d_in, const int* in_sizes, int n_in,
                              void* d_out, int out_size, void* d_ws, size_t ws_size,
                              hipStream_t stream)
{
  const float* h     = (const float*)d_in[0];
  const float* coord = (const float*)d_in[1];
  const int* row = (const int*)d_in[2];
  const int* col = (const int*)d_in[3];
  const float* Wq  = (const float*)d_in[4];
  const float* bq  = (const float*)d_in[5];
  const float* Wkv = (const float*)d_in[6];
  const float* bkv = (const float*)d_in[7];
  const float* Wc1 = (const float*)d_in[8];
  const float* Wc2 = (const float*)d_in[9];
  const int N = in_sizes[0] / H;
  const int E = in_sizes[2];
  float* out = (float*)d_out;

  // layout: [qn fp32 | kn bf16] (dead after k_edge_alpha) <- hn bf16 aliases
  char* p = (char*)d_ws;
  float* qn = (float*)p;
  unsigned short* kn = (unsigned short*)(p + (size_t)N*H*4);
  unsigned short* hn = (unsigned short*)p;
  p += (size_t)N*H*8;
  unsigned short* vn = (unsigned short*)p;  p += (size_t)N*H*2;
  float* mlpout = (float*)p;                p += (size_t)E*3*4;
  int* counts_r = (int*)p;                  p += (size_t)N*CPAD*4;   // padded
  int* counts_c = (int*)p;                  p += (size_t)N*CPAD*4;   // padded
  int* cursor_r = (int*)p;                  p += (size_t)N*CPAD*4;   // padded
  int* cursor_c = (int*)p;                  p += (size_t)N*CPAD*4;   // padded
  int* row_start = (int*)p;                 p += (size_t)(N+1)*4;
  int* cstart = (int*)p;                    p += (size_t)(N+1)*4;
  int* eidx = (int*)p;                      p += (size_t)E*4;
  int* eidx2 = (int*)p;                     p += (size_t)E*4;
  int* bsum = (int*)p;                      p += (size_t)2048*4;
  int* boff = (int*)p;                      p += (size_t)2048*4;
  uint4* w1f = (uint4*)((((size_t)p) + 15) & ~(size_t)15);
  float* Wr6 = (float*)((char*)w1f + 8192*16);
  uint4* ar6f = (uint4*)((char*)Wr6 + 6*512*4);
  float* w2p  = (float*)((char*)ar6f + 512*16);
  float* qwn  = (float*)((char*)w2p + 1536*4);
  uint4* wcat_hi = (uint4*)((char*)qwn + (size_t)N*6*4);
  uint4* wcat_lo = (uint4*)((char*)wcat_hi + 6144*16);
  const size_t need = (size_t)((char*)wcat_lo + 6144*16 - (char*)d_ws);

  if (ws_size < need) {
    k_sentinel<<<(out_size + 255)/256, 256, 0, stream>>>(out, out_size);
    return;
  }

  float* hout = out;
  float* cout = out + (size_t)N*H;
  float* aout = cout + (size_t)N*9;   // raw ar, then normalized alpha

  const int nb = (N + 1023) >> 10;

  k_zero<<<(2*N*CPAD + 255)/256, 256, 0, stream>>>((float*)counts_r, 2*N*CPAD);
  k_prep_w1<<<32, 256, 0, stream>>>(Wc1, w1f);
  k_prep_wcat<<<24, 256, 0, stream>>>(Wq, Wkv, wcat_hi, wcat_lo);
  k_prep_wr6<<<12, 256, 0, stream>>>(Wkv, Wc1, Wr6);
  k_prep_ar6<<<1, 256, 0, stream>>>(Wr6, Wc2, ar6f, w2p);
  k_hist2<<<(E + 255)/256, 256, 0, stream>>>(row, col, counts_r, counts_c, E);
  k_node_mfma<<<(N + 127)/128, 256, 0, stream>>>(h, wcat_hi, wcat_lo, bq, bkv,
                                                 qn, kn, vn, N);
  k_qw<<<(N + 3)/4, 256, 0, stream>>>(qn, Wkv, qwn, N);
  k_scan_local<<<2*nb, 256, 0, stream>>>(counts_r, counts_c, row_start, cstart,
                                         bsum, N, nb);
  k_scan_mid<<<1, 128, 0, stream>>>(bsum, boff, row_start, cstart, N, nb);
  k_scan_add<<<(2*N + 255)/256, 256, 0, stream>>>(row_start, cursor_r,
                                                  cstart, cursor_c, boff, N, nb);
  k_scatter2<<<(E + 255)/256, 256, 0, stream>>>(row, col, cursor_r, eidx,
                                                cursor_c, eidx2, E);
  k_edge_alpha<<<(E + 255)/256, 256, 0, stream>>>(coord, row, col, eidx,
                                                  qn, kn, qwn, aout, E);
  k_row_soft<<<(N + 3)/4, 256, 0, stream>>>(h, coord, col, Wkv, row_start, eidx,
                                            (const unsigned*)vn, aout, hout, N);
  // qn/kn dead from here: hn overwrites their region
  k_node_hn<<<(N + 127)/128, 256, 0, stream>>>((const unsigned*)vn, w1f, hn, N);
  {
    int ntile = (E + 63) >> 6;
    int half = ntile >> 1;
    k_edge_mlp3<<<512, 512, 0, stream>>>(coord, row, col, ar6f, w2p,
                                         hn, eidx2, mlpout, E, 0, half);
    k_edge_mlp3<<<512, 512, 0, stream>>>(coord, row, col, ar6f, w2p,
                                         hn, eidx2, mlpout, E, half, ntile);
  }
  k_coord<<<(N + 15)/16, 256, 0, stream>>>(coord, col, row_start, eidx, aout,
                                           mlpout, cout, N);
}